// Round 1
// baseline (813.939 us; speedup 1.0000x reference)
//
#include <hip/hip_runtime.h>
#include <float.h>
#include <limits.h>

#define RADIUS   0.05f
#define THRESH   3.0f       // Gaussian tail: ~1350 hits per 1M elems; top-64 guaranteed above
#define CAPMAX   4096
#define KMAX     256

__device__ __forceinline__ unsigned fkey(float f) {
  // monotonic float->uint key (ascending)
  unsigned u = __float_as_uint(f);
  return (u & 0x80000000u) ? ~u : (u | 0x80000000u);
}

__global__ void zero_cnt_kernel(int* cnt, int n) {
  int t = blockIdx.x * blockDim.x + threadIdx.x;
  if (t < n) cnt[t] = 0;
}

__global__ __launch_bounds__(256) void collect_kernel(
    const float* __restrict__ hm, int* __restrict__ cnt, uint2* __restrict__ buf,
    int cap, int elems) {
  const int b = blockIdx.y;
  const int nvecTotal = elems >> 2;
  const int chunkVec = nvecTotal / gridDim.x;
  const float4* p = (const float4*)(hm + (size_t)b * elems) + (size_t)blockIdx.x * chunkVec;
  const int baseIdx = blockIdx.x * chunkVec * 4;
  for (int i = threadIdx.x; i < chunkVec; i += blockDim.x) {
    float4 v = p[i];
    int idx = baseIdx + (i << 2);
    if (v.x > THRESH) { int pos = atomicAdd(&cnt[b], 1); if (pos < cap) buf[(size_t)b*cap + pos] = make_uint2(__float_as_uint(v.x), (unsigned)(idx + 0)); }
    if (v.y > THRESH) { int pos = atomicAdd(&cnt[b], 1); if (pos < cap) buf[(size_t)b*cap + pos] = make_uint2(__float_as_uint(v.y), (unsigned)(idx + 1)); }
    if (v.z > THRESH) { int pos = atomicAdd(&cnt[b], 1); if (pos < cap) buf[(size_t)b*cap + pos] = make_uint2(__float_as_uint(v.z), (unsigned)(idx + 2)); }
    if (v.w > THRESH) { int pos = atomicAdd(&cnt[b], 1); if (pos < cap) buf[(size_t)b*cap + pos] = make_uint2(__float_as_uint(v.w), (unsigned)(idx + 3)); }
  }
}

__global__ __launch_bounds__(256) void select_kernel(
    const float* __restrict__ hm, const int* __restrict__ cnt,
    const uint2* __restrict__ buf, int cap, float* __restrict__ out,
    int W, int H, int K, int nk, int elems) {
  const int b   = blockIdx.x;
  const int tid = threadIdx.x;

  __shared__ float cv[CAPMAX];
  __shared__ int   ci[CAPMAX];
  __shared__ float topx[KMAX], topy[KMAX];
  __shared__ float rv[4]; __shared__ int ri[4]; __shared__ int rp[4];
  __shared__ int   smask[KMAX];
  __shared__ float outbuf[2 * KMAX];
  __shared__ int   s_m;
  __shared__ unsigned s_cnt;
  __shared__ int   s_count;

  int m = 0;
  int c = cnt[b];
  bool fast = (cap > 0) && (c >= K) && (c <= cap);

  if (fast) {
    m = c;
    for (int i = tid; i < c; i += blockDim.x) {
      uint2 e = buf[(size_t)b * cap + i];
      cv[i] = __uint_as_float(e.x);
      ci[i] = (int)e.y;
    }
    __syncthreads();
  } else {
    // ---- fallback: exact binary search on key space (data-agnostic) ----
    unsigned lo = 0u, hi = 0xFFFFFFFFu;
    const float4* p = (const float4*)(hm + (size_t)b * elems);
    const int nvec = elems >> 2;
    while (lo < hi) {
      unsigned mid = lo + ((hi - lo) >> 1) + 1u;
      if (tid == 0) s_cnt = 0u;
      __syncthreads();
      unsigned local = 0;
      for (int i = tid; i < nvec; i += blockDim.x) {
        float4 v = p[i];
        local += (fkey(v.x) >= mid) + (fkey(v.y) >= mid) + (fkey(v.z) >= mid) + (fkey(v.w) >= mid);
      }
      atomicAdd(&s_cnt, local);
      __syncthreads();
      unsigned tot = s_cnt;
      if (tot >= (unsigned)K) lo = mid; else hi = mid - 1u;
      __syncthreads();
    }
    if (tid == 0) s_m = 0;
    __syncthreads();
    const float* q = hm + (size_t)b * elems;
    for (int i = tid; i < elems; i += blockDim.x) {
      float v = q[i];
      if (fkey(v) >= lo) {
        int pos = atomicAdd(&s_m, 1);
        if (pos < CAPMAX) { cv[pos] = v; ci[pos] = i; }
      }
    }
    __syncthreads();
    m = s_m < CAPMAX ? s_m : CAPMAX;
  }

  // ---- top-K selection: K rounds of block argmax (val desc, idx asc tiebreak) ----
  const float invW = 1.0f / (float)(W - 1);
  const float invH = 1.0f / (float)(H - 1);
  for (int r = 0; r < K; r++) {
    float bv = -FLT_MAX; int bi = INT_MAX; int bp = -1;
    for (int j = tid; j < m; j += blockDim.x) {
      float v = cv[j];
      int   idx = ci[j];
      if (v > bv || (v == bv && idx < bi)) { bv = v; bi = idx; bp = j; }
    }
    // wave-level shuffle reduce (width 64)
    for (int off = 32; off >= 1; off >>= 1) {
      float ov = __shfl_down(bv, off);
      int   oi = __shfl_down(bi, off);
      int   op = __shfl_down(bp, off);
      if (ov > bv || (ov == bv && oi < bi)) { bv = ov; bi = oi; bp = op; }
    }
    int wid = tid >> 6;
    if ((tid & 63) == 0) { rv[wid] = bv; ri[wid] = bi; rp[wid] = bp; }
    __syncthreads();
    if (tid == 0) {
      float fbv = rv[0]; int fbi = ri[0]; int fbp = rp[0];
      for (int w = 1; w < 4; w++) {
        if (rv[w] > fbv || (rv[w] == fbv && ri[w] < fbi)) { fbv = rv[w]; fbi = ri[w]; fbp = rp[w]; }
      }
      if (fbp >= 0 && fbi != INT_MAX) {
        cv[fbp] = -FLT_MAX; ci[fbp] = INT_MAX;
        int ty = fbi / W;
        int tx = fbi - ty * W;
        topx[r] = (float)tx * invW;   // x = tx/(W-1)
        topy[r] = (float)ty * invH;   // y = ty/(H-1)
      } else {
        topx[r] = 0.0f; topy[r] = 0.0f;
      }
    }
    __syncthreads();
  }

  // ---- greedy sequential NMS (exact reference semantics) ----
  if (tid < K) smask[tid] = 0;
  if (tid == 0) s_count = 0;
  for (int i = tid; i < 2 * nk; i += blockDim.x) outbuf[i] = 0.0f;
  __syncthreads();

  float myx = (tid < K) ? topx[tid] : 0.0f;
  float myy = (tid < K) ? topy[tid] : 0.0f;
  for (int i = 0; i < K; i++) {
    float xi = topx[i], yi = topy[i];
    float dx = myx - xi, dy = myy - yi;
    int cond = (tid < K) && smask[tid] && (sqrtf(dx * dx + dy * dy) < RADIUS);
    int any = __syncthreads_or(cond);
    if (tid == 0) {
      int accept = (!any) && (s_count < nk);
      smask[i] = accept;
      s_count += accept;
    }
    __syncthreads();
  }

  if (tid == 0) {
    int slot = 0;
    for (int i = 0; i < K; i++) {
      if (smask[i]) {
        outbuf[2 * slot]     = topx[i];
        outbuf[2 * slot + 1] = topy[i];
        slot++;
      }
    }
  }
  __syncthreads();

  float* outp = out + (size_t)b * 2 * nk;
  for (int i = tid; i < 2 * nk; i += blockDim.x) outp[i] = outbuf[i];
}

extern "C" void kernel_launch(void* const* d_in, const int* in_sizes, int n_in,
                              void* d_out, int out_size, void* d_ws, size_t ws_size,
                              hipStream_t stream) {
  const float* hm = (const float*)d_in[0];
  const int H = 1024, W = 1024;
  const int elems = H * W;
  int B = in_sizes[0] / elems;                 // 64
  int nk = out_size / (B * 2);                 // 16
  int K = 4 * nk;                              // 64
  if (K > elems) K = elems;
  if (K > KMAX) K = KMAX;

  int* cnt = (int*)d_ws;
  uint2* buf = (uint2*)((char*)d_ws + 256);
  size_t avail = (ws_size > 256) ? (ws_size - 256) : 0;
  long long capl = (long long)(avail / ((size_t)B * sizeof(uint2)));
  int cap = (capl > CAPMAX) ? CAPMAX : (int)capl;
  if (cap < 0) cap = 0;

  zero_cnt_kernel<<<(B + 63) / 64, 64, 0, stream>>>(cnt, B);
  if (cap > 0) {
    dim3 grid(16, B);
    collect_kernel<<<grid, 256, 0, stream>>>(hm, cnt, buf, cap, elems);
  }
  select_kernel<<<B, 256, 0, stream>>>(hm, cnt, buf, cap, (float*)d_out, W, H, K, nk, elems);
}

// Round 2
// 439.367 us; speedup vs baseline: 1.8525x; 1.8525x over previous
//
#include <hip/hip_runtime.h>
#include <float.h>
#include <limits.h>

#define RADIUS 0.05f
#define TH     3.0f      // N(0,1) tail: per-batch mean ~1350 hits, per-block(64K elems) mean ~84
#define LCAP   1024      // per-block LDS hit buffer (mean 84, +99 sigma margin)
#define SORTN  2048      // per-batch sort size (mean 1350, sigma 37 -> +18 sigma margin)

typedef unsigned long long u64;

__device__ __forceinline__ unsigned fkey(float f) {
  unsigned u = __float_as_uint(f);
  return (u & 0x80000000u) ? ~u : (u | 0x80000000u);  // monotonic float->uint
}

__global__ __launch_bounds__(256) void zero_k(unsigned* cnt, int* bad, int B) {
  int t = blockIdx.x * blockDim.x + threadIdx.x;
  if (t < B * 16) cnt[t] = 0u;          // counters padded to 64B lines (stride 16 u32)
  if (t < B) bad[t] = 0;
}

__global__ __launch_bounds__(256) void scan_collect(
    const float* __restrict__ hm, unsigned* __restrict__ cnt, int* __restrict__ bad,
    u64* __restrict__ buf, int bcap, int elems, int chunk) {
  const int b   = blockIdx.y;
  const int tid = threadIdx.x;
  const int vbase = blockIdx.x * chunk;                 // in float4 units
  const float4* p = (const float4*)(hm + (size_t)b * elems) + vbase;

  __shared__ u64 sbuf[LCAP];
  __shared__ unsigned sh, sbase;
  if (tid == 0) sh = 0u;
  __syncthreads();

  auto push = [&](float v, int idx) {
    if (v > TH) {                                       // v>3 => positive => fkey = u|signbit
      unsigned pos = atomicAdd(&sh, 1u);                // LDS atomic: cheap, no XCD traffic
      if (pos < LCAP)
        sbuf[pos] = ((u64)(__float_as_uint(v) | 0x80000000u) << 32) | (unsigned)(~idx);
    }
  };

  int chunkMain = chunk & ~1023;                        // 4 float4 loads in flight per thread
  for (int i = tid; i < chunkMain; i += 1024) {
    float4 v0 = p[i], v1 = p[i + 256], v2 = p[i + 512], v3 = p[i + 768];
    int g0 = (vbase + i) << 2, g1 = (vbase + i + 256) << 2;
    int g2 = (vbase + i + 512) << 2, g3 = (vbase + i + 768) << 2;
    push(v0.x, g0); push(v0.y, g0 + 1); push(v0.z, g0 + 2); push(v0.w, g0 + 3);
    push(v1.x, g1); push(v1.y, g1 + 1); push(v1.z, g1 + 2); push(v1.w, g1 + 3);
    push(v2.x, g2); push(v2.y, g2 + 1); push(v2.z, g2 + 2); push(v2.w, g2 + 3);
    push(v3.x, g3); push(v3.y, g3 + 1); push(v3.z, g3 + 2); push(v3.w, g3 + 3);
  }
  for (int i = chunkMain + tid; i < chunk; i += 256) {  // tail (empty for 1024x1024)
    float4 v = p[i];
    int g = (vbase + i) << 2;
    push(v.x, g); push(v.y, g + 1); push(v.z, g + 2); push(v.w, g + 3);
  }

  __syncthreads();
  unsigned h = sh;
  unsigned stored = h < (unsigned)LCAP ? h : (unsigned)LCAP;
  if (tid == 0) {
    sbase = atomicAdd(&cnt[b * 16], stored);            // ONE global atomic per block
    if (h > (unsigned)LCAP || sbase + stored > (unsigned)bcap) atomicExch(&bad[b], 1);
  }
  __syncthreads();
  unsigned gb = sbase;
  for (unsigned i = tid; i < stored; i += 256) {
    unsigned dst = gb + i;
    if (dst < (unsigned)bcap) buf[(size_t)b * bcap + dst] = sbuf[i];
  }
}

__global__ __launch_bounds__(256) void select_k(
    const float* __restrict__ hm, const unsigned* __restrict__ cnt,
    const int* __restrict__ bad, const u64* __restrict__ buf, int bcap,
    float* __restrict__ out, int W, int H, int K, int nk, int elems) {
  const int b = blockIdx.x, tid = threadIdx.x;

  __shared__ u64 s[SORTN];
  __shared__ unsigned s_cnt;
  __shared__ int s_m;
  __shared__ float topx[64], topy[64];
  __shared__ float outbuf[128];

  int c = 0;
  bool good = false;
  if (bcap > 0) {
    c = (int)cnt[b * 16];
    good = (!bad[b]) && (c >= K) && (c <= bcap) && (c <= SORTN);
  }

  if (good) {
    for (int i = tid; i < SORTN; i += 256)
      s[i] = (i < c) ? buf[(size_t)b * bcap + i] : 0ull;
  } else {
    // ---- exact data-agnostic fallback: binary search K-th key over whole image ----
    unsigned lo = 0u, hi = 0xFFFFFFFFu;
    const float4* p4 = (const float4*)(hm + (size_t)b * elems);
    const int nvec4 = elems >> 2;
    while (lo < hi) {
      unsigned mid = lo + ((hi - lo) >> 1) + 1u;
      if (tid == 0) s_cnt = 0u;
      __syncthreads();
      unsigned local = 0;
      for (int i = tid; i < nvec4; i += 256) {
        float4 v = p4[i];
        local += (fkey(v.x) >= mid) + (fkey(v.y) >= mid) + (fkey(v.z) >= mid) + (fkey(v.w) >= mid);
      }
      atomicAdd(&s_cnt, local);
      __syncthreads();
      if (s_cnt >= (unsigned)K) lo = mid; else hi = mid - 1u;
      __syncthreads();
    }
    if (tid == 0) s_m = 0;
    __syncthreads();
    const float* q = hm + (size_t)b * elems;
    for (int i = tid; i < elems; i += 256) {
      unsigned kk = fkey(q[i]);
      if (kk >= lo) {
        int pos = atomicAdd(&s_m, 1);
        if (pos < SORTN) s[pos] = ((u64)kk << 32) | (unsigned)(~i);
      }
    }
    __syncthreads();
    int c2 = s_m < SORTN ? s_m : SORTN;
    for (int i = tid; i < SORTN; i += 256)
      if (i >= c2) s[i] = 0ull;
  }
  __syncthreads();

  // ---- bitonic sort descending on packed (fkey | ~idx): val desc, idx asc ----
  for (int k2 = 2; k2 <= SORTN; k2 <<= 1) {
    for (int j = k2 >> 1; j > 0; j >>= 1) {
      for (int i = tid; i < SORTN; i += 256) {
        int ix = i ^ j;
        if (ix > i) {
          u64 a = s[i], bb = s[ix];
          bool desc = ((i & k2) == 0);
          bool sw = desc ? (a < bb) : (a > bb);
          if (sw) { s[i] = bb; s[ix] = a; }
        }
      }
      __syncthreads();
    }
  }

  // ---- decode top-K coords ----
  const float invW = 1.0f / (float)(W - 1);
  const float invH = 1.0f / (float)(H - 1);
  if (tid < K) {
    u64 e = s[tid];
    int idx = (int)(~(unsigned)(e & 0xFFFFFFFFu));
    int ty = idx / W;
    int tx = idx - ty * W;
    topx[tid] = (float)tx * invW;
    topy[tid] = (float)ty * invH;
  }
  for (int i = tid; i < 2 * nk; i += 256) outbuf[i] = 0.0f;
  __syncthreads();

  // ---- single-wave greedy NMS (K <= 64): ballot/shfl, zero barriers ----
  if (tid < 64) {
    float myx = (tid < K) ? topx[tid] : 0.0f;
    float myy = (tid < K) ? topy[tid] : 0.0f;
    bool sel = false;
    int cntA = 0;
    for (int i = 0; i < K; i++) {
      float xi = __shfl(myx, i);
      float yi = __shfl(myy, i);
      float dx = myx - xi, dy = myy - yi;
      bool close = sel && (sqrtf(dx * dx + dy * dy) < RADIUS);
      u64 anym = __ballot(close);
      bool accept = (anym == 0ull) && (cntA < nk);
      if (tid == i) sel = accept;
      cntA += accept ? 1 : 0;
    }
    u64 selball = __ballot(sel);
    if (sel) {
      int slot = __popcll(selball & ((1ull << tid) - 1ull));  // score-order compaction
      if (slot < nk) { outbuf[2 * slot] = myx; outbuf[2 * slot + 1] = myy; }
    }
  }
  __syncthreads();

  float* outp = out + (size_t)b * 2 * nk;
  for (int i = tid; i < 2 * nk; i += 256) outp[i] = outbuf[i];
}

extern "C" void kernel_launch(void* const* d_in, const int* in_sizes, int n_in,
                              void* d_out, int out_size, void* d_ws, size_t ws_size,
                              hipStream_t stream) {
  const float* hm = (const float*)d_in[0];
  const int H = 1024, W = 1024;
  const int elems = H * W;
  int B = in_sizes[0] / elems;              // 64
  int nk = out_size / (B * 2);              // 16
  int K = 4 * nk;                           // 64
  if (K > elems) K = elems;
  if (K > 64) K = 64;                       // single-wave NMS bound (problem: K=64)

  // ws layout: cnt B*16 u32 (padded lines) | bad B int | buf B*bcap u64
  unsigned* cnt = (unsigned*)d_ws;
  size_t off_bad = (size_t)B * 16 * sizeof(unsigned);
  int* bad = (int*)((char*)d_ws + off_bad);
  size_t off_buf = (off_bad + (size_t)B * sizeof(int) + 255) & ~(size_t)255;
  u64* buf = (u64*)((char*)d_ws + off_buf);
  int bcap = 0;
  if (ws_size > off_buf) {
    size_t avail = ws_size - off_buf;
    long long capl = (long long)(avail / ((size_t)B * sizeof(u64)));
    bcap = (capl > SORTN) ? SORTN : (int)capl;
  }

  zero_k<<<(B * 16 + 255) / 256, 256, 0, stream>>>(cnt, bad, B);
  if (bcap > 0) {
    const int gx = 16;
    int chunk = (elems >> 2) / gx;          // 16384 float4 per block
    dim3 grid(gx, B);
    scan_collect<<<grid, 256, 0, stream>>>(hm, cnt, bad, buf, bcap, elems, chunk);
  }
  select_k<<<B, 256, 0, stream>>>(hm, cnt, bad, buf, bcap, (float*)d_out, W, H, K, nk, elems);
}